// Round 10
// baseline (49.352 us; speedup 1.0000x reference)
//
#include <hip/hip_runtime.h>

#define BATCH 8
#define CIN   64
#define COUT  64
#define LEN   16384
#define KS    5
#define PADW  2
#define LP    (LEN + 2*PADW)     // 16388 padded rows
#define TT    64

typedef __attribute__((ext_vector_type(8)))  short short8;
typedef __attribute__((ext_vector_type(4)))  float f32x4;

__device__ __forceinline__ unsigned short bf16r(float f) {
    unsigned u = __builtin_bit_cast(unsigned, f);
    u += 0x7FFF + ((u >> 16) & 1);          // RNE
    return (unsigned short)(u >> 16);
}

__device__ __forceinline__ unsigned pack_bf16x2(float a, float b) {
    return (unsigned)bf16r(a) | ((unsigned)bf16r(b) << 16);
}

__device__ __forceinline__ int reflmap(int s) {  // padded idx -> x idx
    return (s < PADW) ? (PADW - s) : ((s < LEN + PADW) ? (s - PADW) : (2*LEN - s));
}

// W (f32 [o][c][k]) -> bf16 A-frags for mfma_f32_16x16x32_bf16, K k-major
// (ck' = ktap*64 + c).  wf[((ot*10 + kk)*64 + lane)*8 + bidx]
__global__ void wfrag_kernel(const float* __restrict__ w, unsigned short* __restrict__ wf) {
    int el = blockIdx.x * 256 + threadIdx.x;          // 20480 total
    int bidx = el & 7;
    int lane = (el >> 3) & 63;
    int kk   = (el >> 9) % 10;
    int ot   = el / 5120;
    int o    = ot * 16 + (lane & 15);
    int kg   = kk * 32 + ((lane >> 4) << 3) + bidx;   // ck' 0..319
    int ktap = kg >> 6;
    int c    = kg & 63;
    wf[el] = bf16r(w[(o * 64 + c) * 5 + ktap]);
}

// Build xT[b][r][c]: bf16 of reflect-padded x, rows r in [0, LP), packed as
// uint words (channels 2cp, 2cp+1). Row = 32 uints = 128 B.
__global__ __launch_bounds__(256) void xpose_kernel(const float* __restrict__ x,
                                                    unsigned* __restrict__ xT) {
    __shared__ unsigned tlds[4][64][33];     // 33792 B, wave-private quadrants

    const int tid  = threadIdx.x;
    const int w    = tid >> 6;
    const int lane = tid & 63;
    const int blk  = blockIdx.x;
    const int b    = blk / 65;
    const int tile = blk - b * 65;           // 65 tiles of 256 rows (last partial)
    const int r0w  = tile * 256 + w * 64;    // wave's first padded row
    const int r    = r0w + lane;
    const int src  = reflmap(min(r, LP - 1));
    const float* xb0 = x + (size_t)b * CIN * LEN;

    // phase A: per channel-pair, coalesced loads; LDS bank = (lane+cp)%32
    #pragma unroll 8
    for (int c = 0; c < 64; c += 2) {
        float v0 = xb0[(size_t)c * LEN + src];
        float v1 = xb0[(size_t)(c + 1) * LEN + src];
        tlds[w][lane][c >> 1] = pack_bf16x2(v0, v1);
    }
    __syncthreads();

    // phase B: contiguous 16B-chunk writes (1 KB per wave-instr)
    unsigned* xTb = xT + (size_t)b * (LP * 32);
    #pragma unroll
    for (int it = 0; it < 8; ++it) {
        int chunk = it * 64 + lane;          // 512 chunks = 64 rows x 128 B
        int rl = chunk >> 3, c8 = chunk & 7;
        int rr = r0w + rl;
        if (rr < LP) {
            uint4 v = *(const uint4*)&tlds[w][rl][c8 * 4];
            *(uint4*)&xTb[(size_t)rr * 32 + c8 * 4] = v;
        }
    }
}

// Hot kernel: no LDS, no barriers, no edge branches.
__global__ __launch_bounds__(256) void deform_mfma_kernel(
    const unsigned* __restrict__ xT, const float* __restrict__ offs,
    const unsigned short* __restrict__ wf, const float* __restrict__ bias,
    float* __restrict__ out)
{
    const int tid  = threadIdx.x;            // 4 waves
    const int bt   = blockIdx.x;
    const int b    = bt >> 8;
    const int t0   = (bt & 255) * TT;
    const int w    = tid >> 6;
    const int lane = tid & 63;
    const int s    = lane >> 4;              // k-chunk slot / A kq group
    const int tc   = t0 + w * 16 + (lane & 15);

    const unsigned* xTb = xT + (size_t)b * (LP * 32);

    float ofr[KS];
    #pragma unroll
    for (int k = 0; k < KS; ++k)
        ofr[k] = offs[(size_t)(b * LEN + tc) * KS + k];

    int i0r[KS]; float frr[KS];
    #pragma unroll
    for (int k = 0; k < KS; ++k) {
        float T = (float)(tc + k) + ofr[k];  // padded coord (t + k + off)
        T = fminf(fmaxf(T, 0.0f), (float)(LP - 1));
        int i0 = (int)floorf(T);
        i0 = min(i0, LP - 2); i0 = max(i0, 0);
        i0r[k] = i0;
        frr[k] = T - (float)i0;
    }

    f32x4 acc0 = {}, acc1 = {}, acc2 = {}, acc3 = {};
    const unsigned short* wfl = wf + (size_t)lane * 8;

#define LERPW(dst, w0, w1, f)                                                  \
    {                                                                          \
        float g0a = __builtin_bit_cast(float, (w0) << 16);                     \
        float g1a = __builtin_bit_cast(float, (w1) << 16);                     \
        float g0b = __builtin_bit_cast(float, (w0) & 0xFFFF0000u);             \
        float g1b = __builtin_bit_cast(float, (w1) & 0xFFFF0000u);             \
        dst = pack_bf16x2(fmaf(f, g1a - g0a, g0a), fmaf(f, g1b - g0b, g0b));   \
    }

#define GSTEP(kk)                                                              \
    {                                                                          \
        const int k = (kk) >> 1;                                               \
        const int m = (((kk) & 1) << 2) + s;         /* chunk 0..7 */          \
        const float f = frr[k];                                                \
        const unsigned* rp = xTb + (size_t)i0r[k] * 32 + m * 4;                \
        uint4 u0 = *(const uint4*)rp;                /* row i0,  8 ch */       \
        uint4 u1 = *(const uint4*)(rp + 32);         /* row i0+1      */       \
        unsigned q0, q1, q2, q3;                                               \
        LERPW(q0, u0.x, u1.x, f) LERPW(q1, u0.y, u1.y, f)                      \
        LERPW(q2, u0.z, u1.z, f) LERPW(q3, u0.w, u1.w, f)                      \
        uint4 pw = {q0, q1, q2, q3};                                           \
        short8 bv = __builtin_bit_cast(short8, pw);                            \
        short8 a0 = *(const short8*)&wfl[(0 * 10 + (kk)) * 512];               \
        short8 a1 = *(const short8*)&wfl[(1 * 10 + (kk)) * 512];               \
        short8 a2 = *(const short8*)&wfl[(2 * 10 + (kk)) * 512];               \
        short8 a3 = *(const short8*)&wfl[(3 * 10 + (kk)) * 512];               \
        acc0 = __builtin_amdgcn_mfma_f32_16x16x32_bf16(a0, bv, acc0, 0, 0, 0); \
        acc1 = __builtin_amdgcn_mfma_f32_16x16x32_bf16(a1, bv, acc1, 0, 0, 0); \
        acc2 = __builtin_amdgcn_mfma_f32_16x16x32_bf16(a2, bv, acc2, 0, 0, 0); \
        acc3 = __builtin_amdgcn_mfma_f32_16x16x32_bf16(a3, bv, acc3, 0, 0, 0); \
    }

    GSTEP(0) GSTEP(1) GSTEP(2) GSTEP(3) GSTEP(4)
    GSTEP(5) GSTEP(6) GSTEP(7) GSTEP(8) GSTEP(9)
#undef GSTEP
#undef LERPW

    // ---- epilogue: C/D col=lane&15 (=tc), row=(lane>>4)*4+r ----
    #pragma unroll
    for (int ot = 0; ot < 4; ++ot) {
        const f32x4 a = (ot == 0) ? acc0 : (ot == 1) ? acc1 : (ot == 2) ? acc2 : acc3;
        #pragma unroll
        for (int r = 0; r < 4; ++r) {
            int o = ot * 16 + s * 4 + r;
            out[((size_t)(b * COUT + o)) * LEN + tc] = a[r] + bias[o];
        }
    }
}

extern "C" void kernel_launch(void* const* d_in, const int* in_sizes, int n_in,
                              void* d_out, int out_size, void* d_ws, size_t ws_size,
                              hipStream_t stream) {
    const float* x    = (const float*)d_in[0];
    const float* offs = (const float*)d_in[1];
    const float* w    = (const float*)d_in[2];
    const float* bias = (const float*)d_in[3];
    float* out = (float*)d_out;

    unsigned short* wf = (unsigned short*)d_ws;                  // 40 KB
    unsigned* xT = (unsigned*)((char*)d_ws + 65536);             // 8*16388*128 B = 16.8 MB

    wfrag_kernel<<<80, 256, 0, stream>>>(w, wf);
    xpose_kernel<<<BATCH * 65, 256, 0, stream>>>(x, xT);
    deform_mfma_kernel<<<BATCH * (LEN / TT), 256, 0, stream>>>(xT, offs, wf, bias, out);
}

// Round 11
// 45.047 us; speedup vs baseline: 1.0956x; 1.0956x over previous
//
#include <hip/hip_runtime.h>

#define BATCH 8
#define CIN   64
#define COUT  64
#define LEN   16384
#define KS    5
#define PADW  2
#define LP    (LEN + 2*PADW)     // 16388 padded rows
#define TTB   256                // cols per block
#define NIT   4                  // subtile iterations per wave (64 cols each)

typedef __attribute__((ext_vector_type(8)))  short short8;
typedef __attribute__((ext_vector_type(4)))  float f32x4;

__device__ __forceinline__ unsigned short bf16r(float f) {
    unsigned u = __builtin_bit_cast(unsigned, f);
    u += 0x7FFF + ((u >> 16) & 1);          // RNE
    return (unsigned short)(u >> 16);
}

__device__ __forceinline__ unsigned pack_bf16x2(float a, float b) {
    return (unsigned)bf16r(a) | ((unsigned)bf16r(b) << 16);
}

__device__ __forceinline__ int reflmap(int s) {  // padded idx -> x idx
    return (s < PADW) ? (PADW - s) : ((s < LEN + PADW) ? (s - PADW) : (2*LEN - s));
}

// W (f32 [o][c][k]) -> bf16 A-frags for mfma_f32_16x16x32_bf16, K k-major
// (ck' = ktap*64 + c).  wf[((ot*10 + kk)*64 + lane)*8 + bidx]
__global__ void wfrag_kernel(const float* __restrict__ w, unsigned short* __restrict__ wf) {
    int el = blockIdx.x * 256 + threadIdx.x;          // 20480 total
    int bidx = el & 7;
    int lane = (el >> 3) & 63;
    int kk   = (el >> 9) % 10;
    int ot   = el / 5120;
    int o    = ot * 16 + (lane & 15);
    int kg   = kk * 32 + ((lane >> 4) << 3) + bidx;   // ck' 0..319
    int ktap = kg >> 6;
    int c    = kg & 63;
    wf[el] = bf16r(w[(o * 64 + c) * 5 + ktap]);
}

// Build xT[b][r][c]: bf16 of reflect-padded x, rows r in [0, LP), packed as
// uint words (channels 2cp, 2cp+1). Row = 32 uints = 128 B.
__global__ __launch_bounds__(256) void xpose_kernel(const float* __restrict__ x,
                                                    unsigned* __restrict__ xT) {
    __shared__ unsigned tlds[4][64][33];     // wave-private quadrants

    const int tid  = threadIdx.x;
    const int w    = tid >> 6;
    const int lane = tid & 63;
    const int blk  = blockIdx.x;
    const int b    = blk / 65;
    const int tile = blk - b * 65;           // 65 tiles of 256 rows (last partial)
    const int r0w  = tile * 256 + w * 64;
    const int r    = r0w + lane;
    const int src  = reflmap(min(r, LP - 1));
    const float* xb0 = x + (size_t)b * CIN * LEN;

    #pragma unroll 8
    for (int c = 0; c < 64; c += 2) {
        float v0 = xb0[(size_t)c * LEN + src];
        float v1 = xb0[(size_t)(c + 1) * LEN + src];
        tlds[w][lane][c >> 1] = pack_bf16x2(v0, v1);
    }
    __syncthreads();

    unsigned* xTb = xT + (size_t)b * (LP * 32);
    #pragma unroll
    for (int it = 0; it < 8; ++it) {
        int chunk = it * 64 + lane;          // 512 chunks = 64 rows x 128 B
        int rl = chunk >> 3, c8 = chunk & 7;
        int rr = r0w + rl;
        if (rr < LP) {
            uint4 v = *(const uint4*)&tlds[w][rl][c8 * 4];
            *(uint4*)&xTb[(size_t)rr * 32 + c8 * 4] = v;
        }
    }
}

// Hot kernel: weights in registers, no LDS, no barriers, branch-free.
__global__ __launch_bounds__(256, 2) void deform_mfma_kernel(
    const unsigned* __restrict__ xT, const float* __restrict__ offs,
    const unsigned short* __restrict__ wf, const float* __restrict__ bias,
    float* __restrict__ out)
{
    const int tid  = threadIdx.x;            // 4 waves
    const int bt   = blockIdx.x;             // 512 blocks
    const int b    = bt >> 6;
    const int t0   = (bt & 63) * TTB;
    const int w    = tid >> 6;
    const int lane = tid & 63;
    const int s    = lane >> 4;              // k-chunk slot / A kq group
    const int col  = lane & 15;

    const unsigned* xTb = xT + (size_t)b * (LP * 32);

    // ---- load all 40 W A-frags into registers (once per wave) ----
    const unsigned short* wfl = wf + (size_t)lane * 8;
    short8 wr[4][10];
    #pragma unroll
    for (int ot = 0; ot < 4; ++ot)
        #pragma unroll
        for (int kk = 0; kk < 10; ++kk)
            wr[ot][kk] = *(const short8*)&wfl[(ot * 10 + kk) * 512];

    // ---- bias for this thread's 16 output rows (once) ----
    float bi[16];
    #pragma unroll
    for (int ot = 0; ot < 4; ++ot)
        #pragma unroll
        for (int r = 0; r < 4; ++r)
            bi[ot * 4 + r] = bias[ot * 16 + s * 4 + r];

#define LERPW(dst, w0, w1, f)                                                  \
    {                                                                          \
        float g0a = __builtin_bit_cast(float, (w0) << 16);                     \
        float g1a = __builtin_bit_cast(float, (w1) << 16);                     \
        float g0b = __builtin_bit_cast(float, (w0) & 0xFFFF0000u);             \
        float g1b = __builtin_bit_cast(float, (w1) & 0xFFFF0000u);             \
        dst = pack_bf16x2(fmaf(f, g1a - g0a, g0a), fmaf(f, g1b - g0b, g0b));   \
    }

    #pragma unroll 1
    for (int it = 0; it < NIT; ++it) {
        const int tc = t0 + it * 64 + w * 16 + col;

        float ofr[KS];
        #pragma unroll
        for (int k = 0; k < KS; ++k)
            ofr[k] = offs[(size_t)(b * LEN + tc) * KS + k];

        int i0r[KS]; float frr[KS];
        #pragma unroll
        for (int k = 0; k < KS; ++k) {
            float T = (float)(tc + k) + ofr[k];
            T = fminf(fmaxf(T, 0.0f), (float)(LP - 1));
            int i0 = (int)floorf(T);
            i0 = min(i0, LP - 2); i0 = max(i0, 0);
            i0r[k] = i0;
            frr[k] = T - (float)i0;
        }

        f32x4 acc0 = {}, acc1 = {}, acc2 = {}, acc3 = {};

#define GSTEP(kk)                                                              \
        {                                                                      \
            const int k = (kk) >> 1;                                           \
            const int m = (((kk) & 1) << 2) + s;                               \
            const float f = frr[k];                                            \
            const unsigned* rp = xTb + (size_t)i0r[k] * 32 + m * 4;            \
            uint4 u0 = *(const uint4*)rp;                                      \
            uint4 u1 = *(const uint4*)(rp + 32);                               \
            unsigned q0, q1, q2, q3;                                           \
            LERPW(q0, u0.x, u1.x, f) LERPW(q1, u0.y, u1.y, f)                  \
            LERPW(q2, u0.z, u1.z, f) LERPW(q3, u0.w, u1.w, f)                  \
            uint4 pw = {q0, q1, q2, q3};                                       \
            short8 bv = __builtin_bit_cast(short8, pw);                        \
            acc0 = __builtin_amdgcn_mfma_f32_16x16x32_bf16(wr[0][kk], bv, acc0, 0, 0, 0); \
            acc1 = __builtin_amdgcn_mfma_f32_16x16x32_bf16(wr[1][kk], bv, acc1, 0, 0, 0); \
            acc2 = __builtin_amdgcn_mfma_f32_16x16x32_bf16(wr[2][kk], bv, acc2, 0, 0, 0); \
            acc3 = __builtin_amdgcn_mfma_f32_16x16x32_bf16(wr[3][kk], bv, acc3, 0, 0, 0); \
        }

        GSTEP(0) GSTEP(1) GSTEP(2) GSTEP(3) GSTEP(4)
        GSTEP(5) GSTEP(6) GSTEP(7) GSTEP(8) GSTEP(9)
#undef GSTEP

        // ---- store: C/D col=lane&15 (=tc), row=(lane>>4)*4+r ----
        #pragma unroll
        for (int ot = 0; ot < 4; ++ot) {
            const f32x4 a = (ot == 0) ? acc0 : (ot == 1) ? acc1 : (ot == 2) ? acc2 : acc3;
            #pragma unroll
            for (int r = 0; r < 4; ++r) {
                int o = ot * 16 + s * 4 + r;
                out[((size_t)(b * COUT + o)) * LEN + tc] = a[r] + bi[ot * 4 + r];
            }
        }
    }
#undef LERPW
}

extern "C" void kernel_launch(void* const* d_in, const int* in_sizes, int n_in,
                              void* d_out, int out_size, void* d_ws, size_t ws_size,
                              hipStream_t stream) {
    const float* x    = (const float*)d_in[0];
    const float* offs = (const float*)d_in[1];
    const float* w    = (const float*)d_in[2];
    const float* bias = (const float*)d_in[3];
    float* out = (float*)d_out;

    unsigned short* wf = (unsigned short*)d_ws;                  // 40 KB
    unsigned* xT = (unsigned*)((char*)d_ws + 65536);             // 8*16388*128 B = 16.8 MB

    wfrag_kernel<<<80, 256, 0, stream>>>(w, wf);
    xpose_kernel<<<BATCH * 65, 256, 0, stream>>>(x, xT);
    deform_mfma_kernel<<<BATCH * (LEN / TTB), 256, 0, stream>>>(xT, offs, wf, bias, out);
}